// Round 2
// 399.201 us; speedup vs baseline: 1.0001x; 1.0001x over previous
//
#include <hip/hip_runtime.h>

// LocalAttention B=8,H=8,T=8192,E=64; 128 buckets of 64; window = prev+own bucket;
// causal; no 1/sqrt(E) scale (faithful to reference).
// One block = (bh, chunk of 8 buckets). K/V LDS ring, XOR-swizzled pad-free layout:
// 48KB LDS -> 3 blocks/CU (was 72.7KB -> 2). Swapped QK^T (mfma(K,Q)) makes each
// q-row's scores lane-local per 16-lane group -> in-register softmax (s_p/s_part
// eliminated). P redistributed to PV A-fragments via v_permlane32/16_swap pairs.

#define Tseq 8192
#define Edim 64
#define NBUK 128
#define BSZ  64
#define NBPC 8                  // buckets per chunk (halved: grid 1024 = 4/CU, 3 resident)
#define NCHUNK (NBUK / NBPC)    // 16
#define KSTR 64
#define VSTR 128

typedef __bf16 bf16_t;
typedef bf16_t bf16x8 __attribute__((ext_vector_type(8)));
typedef bf16_t bf16x4 __attribute__((ext_vector_type(4)));
typedef float  f32x4  __attribute__((ext_vector_type(4)));

static __device__ __forceinline__ unsigned pack2bf16(float a, float b) {
    union { bf16_t h; unsigned short u; } ca, cb;
    ca.h = (bf16_t)a; cb.h = (bf16_t)b;
    return (unsigned)ca.u | ((unsigned)cb.u << 16);
}
static __device__ __forceinline__ float bf16lo(unsigned wd) {
    union { unsigned u; float f; } c; c.u = wd << 16; return c.f;
}
static __device__ __forceinline__ float bf16hi(unsigned wd) {
    union { unsigned u; float f; } c; c.u = wd & 0xffff0000u; return c.f;
}

__global__ __launch_bounds__(256, 3)
void local_attn_kernel(const float* __restrict__ q,
                       const float* __restrict__ k,
                       const float* __restrict__ v,
                       float* __restrict__ out) {
    // 16KB + 16KB + 16KB = 48KB -> 3 blocks/CU
    __shared__ __attribute__((aligned(16))) bf16_t s_khi[2 * BSZ * KSTR];
    __shared__ __attribute__((aligned(16))) bf16_t s_klo[2 * BSZ * KSTR];
    __shared__ __attribute__((aligned(16))) bf16_t s_vt[Edim * VSTR];

    const int t    = threadIdx.x;
    const int l    = t & 63;
    const int w    = t >> 6;
    const int quad = l >> 4;
    const int lq   = l & 15;
    const int t4   = t >> 4;     // K-stage row-within-16
    const int kc4  = t & 15;     // K-stage float4 column

    const int chunk = blockIdx.x;
    const int bh    = blockIdx.y;
    const int cb0   = chunk * NBPC;

    const float* qb = q + (long long)bh * (Tseq * Edim);
    const float* kb = k + (long long)bh * (Tseq * Edim);
    const float* vb = v + (long long)bh * (Tseq * Edim);
    float*       ob = out + (long long)bh * (Tseq * Edim);

    float4 kpre[4];      // next K bucket: 16 floats/thread
    float  vpre[4][4];   // next V bucket: 16 floats/thread
    float4 qpre[4];      // next Q bucket: 16 floats/thread

    auto prefetchKV = [&](int b) {
        #pragma unroll
        for (int it = 0; it < 4; ++it)
            kpre[it] = *(const float4*)(kb + (b * BSZ + it * 16 + t4) * Edim + kc4 * 4);
        #pragma unroll
        for (int it = 0; it < 4; ++it)
            #pragma unroll
            for (int r = 0; r < 4; ++r)
                vpre[it][r] = vb[(b * BSZ + it * 16 + w * 4 + r) * Edim + l];
    };
    auto prefetchQ = [&](int b) {
        const float* qr = qb + (b * BSZ + w * 16 + lq) * Edim;
        #pragma unroll
        for (int ks = 0; ks < 2; ++ks) {
            qpre[2 * ks]     = *(const float4*)(qr + ks * 32 + quad * 8);
            qpre[2 * ks + 1] = *(const float4*)(qr + ks * 32 + quad * 8 + 4);
        }
    };
    auto stageKV = [&](int half) {
        #pragma unroll
        for (int it = 0; it < 4; ++it) {
            float x[4] = {kpre[it].x, kpre[it].y, kpre[it].z, kpre[it].w};
            bf16x4 hi, lo;
            #pragma unroll
            for (int u = 0; u < 4; ++u) {
                bf16_t h = (bf16_t)x[u];
                hi[u] = h;
                lo[u] = (bf16_t)(x[u] - (float)h);
            }
            const int row = half * BSZ + it * 16 + t4;
            const int col = (kc4 * 4) ^ ((row & 7) << 3);   // XOR swizzle (pad-free)
            *(bf16x4*)(s_khi + row * KSTR + col) = hi;
            *(bf16x4*)(s_klo + row * KSTR + col) = lo;
        }
        #pragma unroll
        for (int it = 0; it < 4; ++it) {
            bf16x4 vv;
            #pragma unroll
            for (int r = 0; r < 4; ++r) vv[r] = (bf16_t)vpre[it][r];
            const int col = (half * BSZ + it * 16 + w * 4) ^ ((l & 7) << 3);
            *(bf16x4*)(s_vt + l * VSTR + col) = vv;
        }
    };

    // ---- prologue: stage bucket cb0-1 into ring half 1 (zeros for global bucket 0) ----
    {
        const int bp = cb0 - 1;
        if (bp >= 0) {
            prefetchKV(bp);
        } else {
            #pragma unroll
            for (int it = 0; it < 4; ++it) {
                kpre[it] = make_float4(0.f, 0.f, 0.f, 0.f);
                #pragma unroll
                for (int r = 0; r < 4; ++r) vpre[it][r] = 0.f;
            }
        }
        stageKV(1);
    }
    prefetchKV(cb0);
    prefetchQ(cb0);

    #pragma unroll 2
    for (int i = 0; i < NBPC; ++i) {
        const int b  = cb0 + i;
        const int hc = b & 1;        // ring half of current bucket (cb0 even)
        const int hp = hc ^ 1;       // half of previous bucket

        // ---- stage current bucket; build Q frags (hi/lo split) ----
        stageKV(hc);
        bf16x8 qhi[2], qlo[2];
        #pragma unroll
        for (int ks = 0; ks < 2; ++ks) {
            const float4 f0 = qpre[2 * ks], f1 = qpre[2 * ks + 1];
            float x[8] = {f0.x, f0.y, f0.z, f0.w, f1.x, f1.y, f1.z, f1.w};
            #pragma unroll
            for (int j = 0; j < 8; ++j) {
                bf16_t h = (bf16_t)x[j];
                qhi[ks][j] = h;
                qlo[ks][j] = (bf16_t)(x[j] - (float)h);
            }
        }
        __syncthreads();   // barrier A: staging visible

        // ---- prefetch next bucket (overlaps this bucket's compute) ----
        if (i + 1 < NBPC) { prefetchKV(b + 1); prefetchQ(b + 1); }

        // ---- swapped QK^T: mfma(K, Q) -> lane holds scores of q = w*16+lq,
        //      key j = n*16 + quad*4 + r. Same LDS/global reads as before. ----
        f32x4 acc[8];
        #pragma unroll
        for (int n = 0; n < 8; ++n) {
            const int rowp = ((n < 4) ? hp * BSZ + n * 16 : hc * BSZ + (n - 4) * 16) + lq;
            const int rsw  = (rowp & 7) << 3;
            f32x4 a = {0.f, 0.f, 0.f, 0.f};
            #pragma unroll
            for (int ks = 0; ks < 2; ++ks) {
                const int col = (ks * 32 + quad * 8) ^ rsw;
                const bf16x8 khf = *(const bf16x8*)(s_khi + rowp * KSTR + col);
                const bf16x8 klf = *(const bf16x8*)(s_klo + rowp * KSTR + col);
                a = __builtin_amdgcn_mfma_f32_16x16x32_bf16(khf, qhi[ks], a, 0, 0, 0);
                a = __builtin_amdgcn_mfma_f32_16x16x32_bf16(klf, qhi[ks], a, 0, 0, 0);
                a = __builtin_amdgcn_mfma_f32_16x16x32_bf16(khf, qlo[ks], a, 0, 0, 0);
            }
            acc[n] = a;
        }

        // ---- mask + exp, fully in-register; pack to bf16 pairs ----
        const bool isb0 = (b == 0);
        const int  iq   = w * 16 + lq;          // this lane's q-row
        unsigned W0[8], W1[8];
        #pragma unroll
        for (int n = 0; n < 8; ++n) {
            float p[4];
            #pragma unroll
            for (int r = 0; r < 4; ++r) {
                const int j = n * 16 + quad * 4 + r;     // window key index
                float d = acc[n][r];
                const bool bad = (n < 4) ? isb0 : (j > iq + 64);
                p[r] = __expf(bad ? -1e30f : d);         // exp(-1e30) == 0
            }
            W0[n] = pack2bf16(p[0], p[1]);
            W1[n] = pack2bf16(p[2], p[3]);
        }

        // ---- rowsum from bf16 P (consistent with PV numerator), butterfly over 4 lanes ----
        float rs = 0.f;
        #pragma unroll
        for (int n = 0; n < 8; ++n)
            rs += (bf16lo(W0[n]) + bf16hi(W0[n])) + (bf16lo(W1[n]) + bf16hi(W1[n]));
        rs += __shfl_xor(rs, 16);
        rs += __shfl_xor(rs, 32);
        const float inv_own = 1.0f / rs;        // inverse denom for q = w*16+lq

        // ---- PV: redistribute P into A-fragments with permlane swaps, then MFMA ----
        f32x4 acc2[4];
        #pragma unroll
        for (int n = 0; n < 4; ++n) { acc2[n][0] = 0.f; acc2[n][1] = 0.f; acc2[n][2] = 0.f; acc2[n][3] = 0.f; }
        #pragma unroll
        for (int ks = 0; ks < 4; ++ks) {
            // perfect shuffle: {X.q0,X.q2,Y.q0,Y.q2} / {X.q1,X.q3,Y.q1,Y.q3}
            unsigned x0 = W0[2 * ks], y0 = W0[2 * ks + 1];
            unsigned x1 = W1[2 * ks], y1 = W1[2 * ks + 1];
            asm("v_permlane32_swap_b32 %0, %1" : "+v"(x0), "+v"(y0));
            asm("v_permlane16_swap_b32 %0, %1" : "+v"(x0), "+v"(y0));
            asm("v_permlane32_swap_b32 %0, %1" : "+v"(x1), "+v"(y1));
            asm("v_permlane16_swap_b32 %0, %1" : "+v"(x1), "+v"(y1));
            // lane now holds P[q=lq][ks*32 + quad*8 + 0..7] as words {x0,x1,y0,y1}
            union { unsigned u[4]; bf16x8 v8; } pf;
            pf.u[0] = x0; pf.u[1] = x1; pf.u[2] = y0; pf.u[3] = y1;
            const bf16x8 pa = pf.v8;
            const int jb = (ks < 2) ? hp * BSZ + ks * 32 : hc * BSZ + (ks - 2) * 32;
            #pragma unroll
            for (int n = 0; n < 4; ++n) {
                const int vrow = n * 16 + lq;
                const int vcol = (jb + quad * 8) ^ ((vrow & 7) << 3);
                const bf16x8 vf = *(const bf16x8*)(s_vt + vrow * VSTR + vcol);
                acc2[n] = __builtin_amdgcn_mfma_f32_16x16x32_bf16(pa, vf, acc2[n], 0, 0, 0);
            }
        }

        // ---- gather inv for output rows (C rows = quad*4+r), normalize + store ----
        float invq[4];
        #pragma unroll
        for (int r = 0; r < 4; ++r)
            invq[r] = __shfl(inv_own, (l & 48) | (quad * 4 + r), 64);

        const int orow0 = b * BSZ + w * 16 + quad * 4;
        #pragma unroll
        for (int n = 0; n < 4; ++n)
            #pragma unroll
            for (int r = 0; r < 4; ++r)
                ob[(orow0 + r) * Edim + n * 16 + lq] = acc2[n][r] * invq[r];

        __syncthreads();   // barrier B: ring halves free for next stage
    }
}

extern "C" void kernel_launch(void* const* d_in, const int* in_sizes, int n_in,
                              void* d_out, int out_size, void* d_ws, size_t ws_size,
                              hipStream_t stream) {
    const float* q = (const float*)d_in[0];
    const float* k = (const float*)d_in[1];
    const float* v = (const float*)d_in[2];
    float* out = (float*)d_out;
    dim3 grid(NCHUNK, 64);   // 16 chunks x 64 bh = 1024 blocks; 48KB LDS -> 3/CU resident
    local_attn_kernel<<<grid, dim3(256), 0, stream>>>(q, k, v, out);
}